// Round 1
// baseline (7251.198 us; speedup 1.0000x reference)
//
#include <hip/hip_runtime.h>
#include <math.h>

#define N_Q 32768
#define K_C 8192
#define D_DIM 512

// ---------------- kernel 1: normalize emb rows -> wnT[d][k] (transposed) + wnorm2[k]
__global__ void k_normw(const float* __restrict__ w, float* __restrict__ wnT,
                        float* __restrict__ wnorm2) {
    __shared__ float red[4];
    __shared__ float s_n;
    int k = blockIdx.x;
    int t = threadIdx.x;            // 256 threads
    int lane = t & 63, wid = t >> 6;
    float v0 = w[(size_t)k * D_DIM + t];
    float v1 = w[(size_t)k * D_DIM + t + 256];
    float ss = fmaf(v0, v0, v1 * v1);
    for (int off = 32; off; off >>= 1) ss += __shfl_down(ss, off, 64);
    if (lane == 0) red[wid] = ss;
    __syncthreads();
    if (t == 0) s_n = fmaxf(sqrtf(red[0] + red[1] + red[2] + red[3]), 1e-12f);
    __syncthreads();
    float n = s_n;
    float a0 = v0 / n, a1 = v1 / n;
    wnT[(size_t)t * K_C + k] = a0;
    wnT[(size_t)(t + 256) * K_C + k] = a1;
    float s2 = fmaf(a0, a0, a1 * a1);
    for (int off = 32; off; off >>= 1) s2 += __shfl_down(s2, off, 64);
    __syncthreads();
    if (lane == 0) red[wid] = s2;
    __syncthreads();
    if (t == 0) wnorm2[k] = red[0] + red[1] + red[2] + red[3];
}

// ---------------- kernel 2: ||x_n|| per row (one wave per row)
__global__ void k_normx(const float* __restrict__ x, float* __restrict__ xnorm) {
    int wid = threadIdx.x >> 6, lane = threadIdx.x & 63;
    int n = blockIdx.x * 4 + wid;
    const float* xr = x + (size_t)n * D_DIM;
    float ss = 0.f;
    #pragma unroll
    for (int i = 0; i < 8; ++i) {
        float v = xr[lane + i * 64];
        ss = fmaf(v, v, ss);
    }
    for (int off = 32; off; off >>= 1) ss += __shfl_down(ss, off, 64);
    if (lane == 0) xnorm[n] = fmaxf(sqrtf(ss), 1e-12f);
}

// component pick, dd must be a compile-time constant after unrolling
#define XCOMP(v, dd) ((dd) == 0 ? (v).x : (dd) == 1 ? (v).y : (dd) == 2 ? (v).z : (v).w)

// ---------------- kernel 3: main score + argmin
// block: 256 threads = 32 (tk) x 8 (tq). q-tile = 32 rows in LDS.
// thread register tile: rq=4 (q = tq*4..+3) x rk=8 (k = kt + tk*2 + j*64 + r)
__global__ __launch_bounds__(256, 2) void k_score(const float* __restrict__ x,
                                                  const float* __restrict__ wnT,
                                                  const float* __restrict__ wnorm2,
                                                  const float* __restrict__ xnorm,
                                                  int* __restrict__ idx_out,
                                                  float* __restrict__ idxf) {
    __shared__ __align__(16) float xs[32][D_DIM];   // 64 KB
    int n0 = blockIdx.x * 32;
    for (int i = threadIdx.x; i < 32 * D_DIM; i += 256) {
        int q = i >> 9, d = i & 511;
        xs[q][d] = x[(size_t)(n0 + q) * D_DIM + d] / xnorm[n0 + q];
    }
    __syncthreads();

    int tk = threadIdx.x & 31, tq = threadIdx.x >> 5;
    float best[4];
    int bestk[4];
    #pragma unroll
    for (int i = 0; i < 4; ++i) { best[i] = INFINITY; bestk[i] = 0; }

    for (int kt = 0; kt < K_C; kt += 256) {
        float acc[4][8];
        #pragma unroll
        for (int i = 0; i < 4; ++i)
            #pragma unroll
            for (int j = 0; j < 8; ++j) acc[i][j] = 0.f;

        const float* wp = wnT + kt + (tk << 1);
        const float* wd = wp;
        for (int d = 0; d < D_DIM; d += 4) {
            float4 xf[4];
            #pragma unroll
            for (int i = 0; i < 4; ++i)
                xf[i] = *(const float4*)&xs[(tq << 2) + i][d];
            #pragma unroll
            for (int dd = 0; dd < 4; ++dd) {
                float2 w0 = *(const float2*)(wd + 0);
                float2 w1 = *(const float2*)(wd + 64);
                float2 w2 = *(const float2*)(wd + 128);
                float2 w3 = *(const float2*)(wd + 192);
                #pragma unroll
                for (int i = 0; i < 4; ++i) {
                    float xv = XCOMP(xf[i], dd);
                    acc[i][0] = fmaf(xv, w0.x, acc[i][0]);
                    acc[i][1] = fmaf(xv, w0.y, acc[i][1]);
                    acc[i][2] = fmaf(xv, w1.x, acc[i][2]);
                    acc[i][3] = fmaf(xv, w1.y, acc[i][3]);
                    acc[i][4] = fmaf(xv, w2.x, acc[i][4]);
                    acc[i][5] = fmaf(xv, w2.y, acc[i][5]);
                    acc[i][6] = fmaf(xv, w3.x, acc[i][6]);
                    acc[i][7] = fmaf(xv, w3.y, acc[i][7]);
                }
                wd += K_C;
            }
        }
        // scores: dist = wnorm2[k] - 2*dot  (+||xn||^2 is constant per row)
        #pragma unroll
        for (int i = 0; i < 4; ++i) {
            #pragma unroll
            for (int j = 0; j < 4; ++j) {
                #pragma unroll
                for (int r = 0; r < 2; ++r) {
                    int kk = kt + (tk << 1) + (j << 6) + r;
                    float s = fmaf(-2.f, acc[i][j * 2 + r], wnorm2[kk]);
                    if (s < best[i] || (s == best[i] && kk < bestk[i])) {
                        best[i] = s; bestk[i] = kk;
                    }
                }
            }
        }
    }
    // reduce across the 32 tk lanes (width-32 groups within the wave)
    #pragma unroll
    for (int i = 0; i < 4; ++i) {
        float b = best[i]; int bk = bestk[i];
        for (int off = 16; off; off >>= 1) {
            float b2 = __shfl_down(b, off, 32);
            int k2 = __shfl_down(bk, off, 32);
            if (b2 < b || (b2 == b && k2 < bk)) { b = b2; bk = k2; }
        }
        if (tk == 0) {
            int n = n0 + (tq << 2) + i;
            idx_out[n] = bk;
            idxf[n] = (float)bk;
        }
    }
}

// ---------------- kernel 4: gather quantized rows, write output, per-block loss partial
__global__ void k_gather(const float* __restrict__ x, const float* __restrict__ emb,
                         const float* __restrict__ xnorm, const int* __restrict__ idx,
                         float* __restrict__ qout, float* __restrict__ partials) {
    __shared__ float red[4];
    int t = threadIdx.x, lane = t & 63, wid = t >> 6;
    int n = blockIdx.x * 4 + wid;
    int k = idx[n];
    const float* er = emb + (size_t)k * D_DIM + lane * 8;
    float4 e0 = *(const float4*)er;
    float4 e1 = *(const float4*)(er + 4);
    float ss = e0.x * e0.x + e0.y * e0.y + e0.z * e0.z + e0.w * e0.w
             + e1.x * e1.x + e1.y * e1.y + e1.z * e1.z + e1.w * e1.w;
    for (int off = 32; off; off >>= 1) ss += __shfl_down(ss, off, 64);
    ss = __shfl(ss, 0, 64);
    float nn = fmaxf(sqrtf(ss), 1e-12f);
    float4 q0, q1;
    q0.x = e0.x / nn; q0.y = e0.y / nn; q0.z = e0.z / nn; q0.w = e0.w / nn;
    q1.x = e1.x / nn; q1.y = e1.y / nn; q1.z = e1.z / nn; q1.w = e1.w / nn;

    const float* xr = x + (size_t)n * D_DIM + lane * 8;
    float4 x0 = *(const float4*)xr;
    float4 x1 = *(const float4*)(xr + 4);
    float xn = xnorm[n];
    float d0 = x0.x / xn - q0.x, d1 = x0.y / xn - q0.y;
    float d2 = x0.z / xn - q0.z, d3 = x0.w / xn - q0.w;
    float d4 = x1.x / xn - q1.x, d5 = x1.y / xn - q1.y;
    float d6 = x1.z / xn - q1.z, d7 = x1.w / xn - q1.w;
    float ds = d0 * d0 + d1 * d1 + d2 * d2 + d3 * d3
             + d4 * d4 + d5 * d5 + d6 * d6 + d7 * d7;

    float* qo = qout + (size_t)n * D_DIM + lane * 8;
    *(float4*)qo = q0;
    *(float4*)(qo + 4) = q1;

    for (int off = 32; off; off >>= 1) ds += __shfl_down(ds, off, 64);
    if (lane == 0) red[wid] = ds;
    __syncthreads();
    if (t == 0) partials[blockIdx.x] = red[0] + red[1] + red[2] + red[3];
}

// ---------------- kernel 5: deterministic final loss reduction
__global__ void k_loss(const float* __restrict__ partials, float* __restrict__ out_loss) {
    __shared__ float red[4];
    int t = threadIdx.x, lane = t & 63, wid = t >> 6;
    float s = 0.f;
    for (int i = t; i < 8192; i += 256) s += partials[i];
    for (int off = 32; off; off >>= 1) s += __shfl_down(s, off, 64);
    if (lane == 0) red[wid] = s;
    __syncthreads();
    if (t == 0)
        out_loss[0] = (red[0] + red[1] + red[2] + red[3]) * (1.25f / ((float)N_Q * (float)D_DIM));
}

extern "C" void kernel_launch(void* const* d_in, const int* in_sizes, int n_in,
                              void* d_out, int out_size, void* d_ws, size_t ws_size,
                              hipStream_t stream) {
    (void)in_sizes; (void)n_in; (void)out_size; (void)ws_size;
    const float* x = (const float*)d_in[0];
    const float* w = (const float*)d_in[1];

    float* out = (float*)d_out;
    float* qout = out;                                  // N*D
    float* loss = out + (size_t)N_Q * D_DIM;            // 1
    float* idxf = loss + 1;                             // N

    float* ws = (float*)d_ws;
    float* wnT = ws;                                    // D*K floats (16 MB)
    float* wnorm2 = ws + (size_t)D_DIM * K_C;           // K
    float* xnorm = wnorm2 + K_C;                        // N
    int* idx = (int*)(xnorm + N_Q);                     // N ints
    float* partials = (float*)(idx + N_Q);              // 8192 floats

    k_normw<<<K_C, 256, 0, stream>>>(w, wnT, wnorm2);
    k_normx<<<N_Q / 4, 256, 0, stream>>>(x, xnorm);
    k_score<<<N_Q / 32, 256, 0, stream>>>(x, wnT, wnorm2, xnorm, idx, idxf);
    k_gather<<<N_Q / 4, 256, 0, stream>>>(x, w, xnorm, idx, qout, partials);
    k_loss<<<1, 256, 0, stream>>>(partials, loss);
}

// Round 2
// 908.981 us; speedup vs baseline: 7.9773x; 7.9773x over previous
//
#include <hip/hip_runtime.h>
#include <math.h>
#include <stdint.h>

#define N_Q 32768
#define K_C 8192
#define D_DIM 512

typedef __attribute__((ext_vector_type(8))) short bf16x8;
typedef __attribute__((ext_vector_type(4))) float f32x4;

typedef const __attribute__((address_space(1))) void gv_t;
typedef __attribute__((address_space(3))) void lv_t;

static __device__ __forceinline__ void gl16(const void* g, void* l) {
    __builtin_amdgcn_global_load_lds((gv_t*)g, (lv_t*)l, 16, 0, 0);
}

static __device__ __forceinline__ unsigned short f2bf(float f) {
    unsigned u = __float_as_uint(f);
    unsigned r = u + 0x7fffu + ((u >> 16) & 1u);
    return (unsigned short)(r >> 16);
}
static __device__ __forceinline__ float bf2f(unsigned short h) {
    return __uint_as_float(((unsigned)h) << 16);
}

// ---------------- kernel 1: normalize emb rows -> wn_hi/wn_lo [k][d] bf16 + wnorm2[k]
__global__ void k_normw(const float* __restrict__ w, unsigned short* __restrict__ wh,
                        unsigned short* __restrict__ wl, float* __restrict__ wnorm2) {
    __shared__ float red[4];
    __shared__ float s_n;
    int k = blockIdx.x;
    int t = threadIdx.x;            // 256 threads
    int lane = t & 63, wid = t >> 6;
    float v0 = w[(size_t)k * D_DIM + t];
    float v1 = w[(size_t)k * D_DIM + t + 256];
    float ss = fmaf(v0, v0, v1 * v1);
    for (int off = 32; off; off >>= 1) ss += __shfl_down(ss, off, 64);
    if (lane == 0) red[wid] = ss;
    __syncthreads();
    if (t == 0) s_n = fmaxf(sqrtf(red[0] + red[1] + red[2] + red[3]), 1e-12f);
    __syncthreads();
    float n = s_n;
    float a0 = v0 / n, a1 = v1 / n;
    unsigned short h0 = f2bf(a0), h1 = f2bf(a1);
    wh[(size_t)k * D_DIM + t] = h0;
    wh[(size_t)k * D_DIM + t + 256] = h1;
    wl[(size_t)k * D_DIM + t] = f2bf(a0 - bf2f(h0));
    wl[(size_t)k * D_DIM + t + 256] = f2bf(a1 - bf2f(h1));
    float s2 = fmaf(a0, a0, a1 * a1);
    for (int off = 32; off; off >>= 1) s2 += __shfl_down(s2, off, 64);
    __syncthreads();
    if (lane == 0) red[wid] = s2;
    __syncthreads();
    if (t == 0) wnorm2[k] = red[0] + red[1] + red[2] + red[3];
}

// ---------------- kernel 2: ||x_n|| per row + xn_hi/xn_lo [n][d] bf16
__global__ void k_normx(const float* __restrict__ x, float* __restrict__ xnorm,
                        unsigned short* __restrict__ xh, unsigned short* __restrict__ xl) {
    int wid = threadIdx.x >> 6, lane = threadIdx.x & 63;
    int n = blockIdx.x * 4 + wid;
    const float* xr = x + (size_t)n * D_DIM;
    float v[8];
    float ss = 0.f;
    #pragma unroll
    for (int i = 0; i < 8; ++i) {
        v[i] = xr[lane + i * 64];
        ss = fmaf(v[i], v[i], ss);
    }
    for (int off = 32; off; off >>= 1) ss += __shfl_down(ss, off, 64);
    ss = __shfl(ss, 0, 64);
    float nrm = fmaxf(sqrtf(ss), 1e-12f);
    if (lane == 0) xnorm[n] = nrm;
    #pragma unroll
    for (int i = 0; i < 8; ++i) {
        float a = v[i] / nrm;
        unsigned short h = f2bf(a);
        size_t o = (size_t)n * D_DIM + lane + i * 64;
        xh[o] = h;
        xl[o] = f2bf(a - bf2f(h));
    }
}

// ---------------- kernel 3: init packed argmin
__global__ void k_init(unsigned long long* __restrict__ p) {
    p[blockIdx.x * 256 + threadIdx.x] = 0xFFFFFFFFFFFFFFFFull;
}

// ---------------- kernel 4: MFMA score + argmin
// Block 256 thr = 4 waves (wm,wn in 2x2). Tile BM=BN=128, BK=32.
// 3-pass bf16 hi/lo split: dot = hh + hl + lh (lo*lo dropped, ~5e-8 RMS).
// LDS tiles [128 rows][32 d] bf16, chunk-swizzled: phys = r*4 + (kg ^ ((r>>1)&3)).
__global__ __launch_bounds__(256, 2) void k_score(
    const unsigned short* __restrict__ xh, const unsigned short* __restrict__ xl,
    const unsigned short* __restrict__ wh, const unsigned short* __restrict__ wl,
    const float* __restrict__ wnorm2, unsigned long long* __restrict__ pmin)
{
    __shared__ __align__(16) unsigned short sAh[128 * 32];
    __shared__ __align__(16) unsigned short sAl[128 * 32];
    __shared__ __align__(16) unsigned short sBh[128 * 32];
    __shared__ __align__(16) unsigned short sBl[128 * 32];

    int tid = threadIdx.x;
    int lane = tid & 63, wid = tid >> 6;
    int wm = wid >> 1, wn = wid & 1;
    int k0 = blockIdx.x * 128;
    int n0 = blockIdx.y * 128;

    f32x4 acc[4][4];
    #pragma unroll
    for (int i = 0; i < 4; ++i)
        #pragma unroll
        for (int j = 0; j < 4; ++j) acc[i][j] = (f32x4){0.f, 0.f, 0.f, 0.f};

    // staging: physical chunk p -> logical row r = p>>2, kg = (p&3) ^ ((r>>1)&3)
    int p0 = wid * 64 + lane;
    int p1 = (4 + wid) * 64 + lane;
    int r0 = p0 >> 2, kg0 = (p0 & 3) ^ ((r0 >> 1) & 3);
    int r1 = p1 >> 2, kg1 = (p1 & 3) ^ ((r1 >> 1) & 3);
    size_t aoff0 = (size_t)(n0 + r0) * D_DIM + kg0 * 8;
    size_t aoff1 = (size_t)(n0 + r1) * D_DIM + kg1 * 8;
    size_t boff0 = (size_t)(k0 + r0) * D_DIM + kg0 * 8;
    size_t boff1 = (size_t)(k0 + r1) * D_DIM + kg1 * 8;
    unsigned lb0 = (unsigned)(wid * 64) * 16u;        // byte offset, it=0
    unsigned lb1 = (unsigned)((4 + wid) * 64) * 16u;  // byte offset, it=1

    int c15 = lane & 15, g = lane >> 4;
    int ach[4], bch[4];
    #pragma unroll
    for (int f = 0; f < 4; ++f) {
        int ar = wm * 64 + f * 16 + c15;
        ach[f] = ar * 4 + (g ^ ((ar >> 1) & 3));
        int br = wn * 64 + f * 16 + c15;
        bch[f] = br * 4 + (g ^ ((br >> 1) & 3));
    }

    for (int dt = 0; dt < 16; ++dt) {
        int d0 = dt * 32;
        __syncthreads();
        gl16(xh + aoff0 + d0, (char*)sAh + lb0);
        gl16(xh + aoff1 + d0, (char*)sAh + lb1);
        gl16(xl + aoff0 + d0, (char*)sAl + lb0);
        gl16(xl + aoff1 + d0, (char*)sAl + lb1);
        gl16(wh + boff0 + d0, (char*)sBh + lb0);
        gl16(wh + boff1 + d0, (char*)sBh + lb1);
        gl16(wl + boff0 + d0, (char*)sBl + lb0);
        gl16(wl + boff1 + d0, (char*)sBl + lb1);
        __syncthreads();

        bf16x8 ah[4], al[4], bh[4], bl[4];
        #pragma unroll
        for (int f = 0; f < 4; ++f) {
            ah[f] = *(const bf16x8*)((const char*)sAh + ach[f] * 16);
            al[f] = *(const bf16x8*)((const char*)sAl + ach[f] * 16);
            bh[f] = *(const bf16x8*)((const char*)sBh + bch[f] * 16);
            bl[f] = *(const bf16x8*)((const char*)sBl + bch[f] * 16);
        }
        #pragma unroll
        for (int i = 0; i < 4; ++i)
            #pragma unroll
            for (int j = 0; j < 4; ++j) {
                acc[i][j] = __builtin_amdgcn_mfma_f32_16x16x32_bf16(ah[i], bh[j], acc[i][j], 0, 0, 0);
                acc[i][j] = __builtin_amdgcn_mfma_f32_16x16x32_bf16(ah[i], bl[j], acc[i][j], 0, 0, 0);
                acc[i][j] = __builtin_amdgcn_mfma_f32_16x16x32_bf16(al[i], bh[j], acc[i][j], 0, 0, 0);
            }
    }

    // epilogue: dist = wnorm2[k] - 2*dot ; argmin with min-index tie-break
    float w2[4];
    #pragma unroll
    for (int j = 0; j < 4; ++j) w2[j] = wnorm2[k0 + wn * 64 + j * 16 + c15];

    #pragma unroll
    for (int i = 0; i < 4; ++i) {
        #pragma unroll
        for (int reg = 0; reg < 4; ++reg) {
            float bv = INFINITY;
            int bk = 0x7fffffff;
            #pragma unroll
            for (int j = 0; j < 4; ++j) {
                float v = fmaf(-2.f, acc[i][j][reg], w2[j]);
                int kk = k0 + wn * 64 + j * 16 + c15;
                if (v < bv || (v == bv && kk < bk)) { bv = v; bk = kk; }
            }
            for (int off = 8; off; off >>= 1) {
                float v2 = __shfl_xor(bv, off, 16);
                int k2 = __shfl_xor(bk, off, 16);
                if (v2 < bv || (v2 == bv && k2 < bk)) { bv = v2; bk = k2; }
            }
            if (c15 == 0) {
                int row = n0 + wm * 64 + i * 16 + g * 4 + reg;
                unsigned ub = __float_as_uint(bv);
                ub = (ub & 0x80000000u) ? ~ub : (ub | 0x80000000u);
                unsigned long long pk = ((unsigned long long)ub << 32) | (unsigned)bk;
                atomicMin(&pmin[row], pk);
            }
        }
    }
}

// ---------------- kernel 5: gather quantized rows, write output + idxf, loss partials
__global__ void k_gather(const float* __restrict__ x, const float* __restrict__ emb,
                         const float* __restrict__ xnorm,
                         const unsigned long long* __restrict__ pmin,
                         float* __restrict__ qout, float* __restrict__ idxf,
                         float* __restrict__ partials) {
    __shared__ float red[4];
    int t = threadIdx.x, lane = t & 63, wid = t >> 6;
    int n = blockIdx.x * 4 + wid;
    int k = (int)(unsigned)(pmin[n] & 0xffffffffull);
    const float* er = emb + (size_t)k * D_DIM + lane * 8;
    float4 e0 = *(const float4*)er;
    float4 e1 = *(const float4*)(er + 4);
    float ss = e0.x * e0.x + e0.y * e0.y + e0.z * e0.z + e0.w * e0.w
             + e1.x * e1.x + e1.y * e1.y + e1.z * e1.z + e1.w * e1.w;
    for (int off = 32; off; off >>= 1) ss += __shfl_down(ss, off, 64);
    ss = __shfl(ss, 0, 64);
    float nn = fmaxf(sqrtf(ss), 1e-12f);
    float4 q0, q1;
    q0.x = e0.x / nn; q0.y = e0.y / nn; q0.z = e0.z / nn; q0.w = e0.w / nn;
    q1.x = e1.x / nn; q1.y = e1.y / nn; q1.z = e1.z / nn; q1.w = e1.w / nn;

    const float* xr = x + (size_t)n * D_DIM + lane * 8;
    float4 x0 = *(const float4*)xr;
    float4 x1 = *(const float4*)(xr + 4);
    float xn = xnorm[n];
    float d0 = x0.x / xn - q0.x, d1 = x0.y / xn - q0.y;
    float d2 = x0.z / xn - q0.z, d3 = x0.w / xn - q0.w;
    float d4 = x1.x / xn - q1.x, d5 = x1.y / xn - q1.y;
    float d6 = x1.z / xn - q1.z, d7 = x1.w / xn - q1.w;
    float ds = d0 * d0 + d1 * d1 + d2 * d2 + d3 * d3
             + d4 * d4 + d5 * d5 + d6 * d6 + d7 * d7;

    float* qo = qout + (size_t)n * D_DIM + lane * 8;
    *(float4*)qo = q0;
    *(float4*)(qo + 4) = q1;
    if (lane == 0) idxf[n] = (float)k;

    for (int off = 32; off; off >>= 1) ds += __shfl_down(ds, off, 64);
    if (lane == 0) red[wid] = ds;
    __syncthreads();
    if (t == 0) partials[blockIdx.x] = red[0] + red[1] + red[2] + red[3];
}

// ---------------- kernel 6: deterministic final loss reduction
__global__ void k_loss(const float* __restrict__ partials, float* __restrict__ out_loss) {
    __shared__ float red[4];
    int t = threadIdx.x, lane = t & 63, wid = t >> 6;
    float s = 0.f;
    for (int i = t; i < 8192; i += 256) s += partials[i];
    for (int off = 32; off; off >>= 1) s += __shfl_down(s, off, 64);
    if (lane == 0) red[wid] = s;
    __syncthreads();
    if (t == 0)
        out_loss[0] = (red[0] + red[1] + red[2] + red[3]) * (1.25f / ((float)N_Q * (float)D_DIM));
}

extern "C" void kernel_launch(void* const* d_in, const int* in_sizes, int n_in,
                              void* d_out, int out_size, void* d_ws, size_t ws_size,
                              hipStream_t stream) {
    (void)in_sizes; (void)n_in; (void)out_size; (void)ws_size;
    const float* x = (const float*)d_in[0];
    const float* w = (const float*)d_in[1];

    float* out = (float*)d_out;
    float* qout = out;                                  // N*D f32
    float* loss = out + (size_t)N_Q * D_DIM;            // 1
    float* idxf = loss + 1;                             // N

    // xn bf16 hi/lo scratch lives in the qout region (exactly 2*N*D shorts),
    // consumed by k_score, then overwritten by k_gather's final output.
    unsigned short* xh = (unsigned short*)qout;         // N*D shorts
    unsigned short* xl = xh + (size_t)N_Q * D_DIM;      // N*D shorts

    char* ws = (char*)d_ws;
    unsigned short* wh = (unsigned short*)ws;                       // K*D shorts (8MB)
    unsigned short* wl = wh + (size_t)K_C * D_DIM;                  // 8MB
    float* wnorm2 = (float*)(wl + (size_t)K_C * D_DIM);             // K
    float* xnorm = wnorm2 + K_C;                                    // N
    unsigned long long* pmin = (unsigned long long*)(xnorm + N_Q);  // N u64
    float* partials = (float*)(pmin + N_Q);                         // 8192

    k_normw<<<K_C, 256, 0, stream>>>(w, wh, wl, wnorm2);
    k_normx<<<N_Q / 4, 256, 0, stream>>>(x, xnorm, xh, xl);
    k_init<<<N_Q / 256, 256, 0, stream>>>(pmin);
    dim3 grid(K_C / 128, N_Q / 128);
    k_score<<<grid, 256, 0, stream>>>(xh, xl, wh, wl, wnorm2, pmin);
    k_gather<<<N_Q / 4, 256, 0, stream>>>(x, w, xnorm, pmin, qout, idxf, partials);
    k_loss<<<1, 256, 0, stream>>>(partials, loss);
}